// Round 1
// baseline (187.363 us; speedup 1.0000x reference)
//
#include <hip/hip_runtime.h>

// SelfAttention: x[8,2048,512] f32, W[3,512,512] f32 -> out[8,2048,512] f32
// scale = 1/sqrt(64) = 0.125 (module hardcodes 64, not d)
//
// Pipeline (all bf16 MFMA, fp32 accum):
//  1. convert x -> bf16            2. transpose+convert W -> Wt bf16
//  3. QKV gemm (C = A.Bt form)     4. scores = Q.Kt * 0.125 -> bf16
//  5. row softmax in place         6. out = P.V (via Vt) -> f32

typedef unsigned short u16;
typedef unsigned int u32;

using bf16x8 = __attribute__((ext_vector_type(8))) short;   // 8 bf16 (guide-verified frag type)
using f32x4  = __attribute__((ext_vector_type(4))) float;
using u16x4  = __attribute__((ext_vector_type(4))) u16;

__device__ __forceinline__ u16 f2bf(float f) {
  u32 u = __float_as_uint(f);
  u32 r = (u + 0x7FFFu + ((u >> 16) & 1u)) >> 16;   // RNE
  return (u16)r;
}
__device__ __forceinline__ float bf2f(u16 h) {
  return __uint_as_float(((u32)h) << 16);
}

// ---------------------------------------------------------------------------
// Shared GEMM mainloop: C[128x128] += A[128xK] . B[128xK]^T  (both row-major,
// K contiguous). 256 threads = 4 waves in 2x2; per wave 64x64 = 4x4 frags of
// 16x16x32 bf16 MFMA. Staging via global_load_lds width 16 (m97 structure).
// ---------------------------------------------------------------------------
__device__ __forceinline__ void gemm_bt_mainloop(
    const u16* __restrict__ Ab,   // A base incl. m0*K
    const u16* __restrict__ Bb,   // B base incl. n0*K
    int K, u16* As, u16* Bs, f32x4 (&acc)[4][4])
{
  const int tid = threadIdx.x;
  const int w = tid >> 6, l = tid & 63;
  const int wr = w >> 1, wc = w & 1;
  const int srow = l >> 2;            // staging: 4 lanes per 64B row-chunk
  const int skof = (l & 3) * 8;       // staging k offset (elems)
  const int fr = l & 15;              // frag row/col
  const int k8 = (l >> 4) * 8;        // frag k base (elems)

  const u16* aSrc = Ab + (size_t)(w * 32 + srow) * K + skof;
  const u16* bSrc = Bb + (size_t)(w * 32 + srow) * K + skof;
  u16* aDst = As + w * 1024;          // wave-uniform LDS base (HW adds lane*16B)
  u16* bDst = Bs + w * 1024;
  const int rowK16 = 16 * K;

  for (int kt = 0; kt < K; kt += 32) {
    __syncthreads();  // previous tile fully consumed
    __builtin_amdgcn_global_load_lds((const __attribute__((address_space(1))) void*)(aSrc + kt),
                                     (__attribute__((address_space(3))) void*)(aDst), 16, 0, 0);
    __builtin_amdgcn_global_load_lds((const __attribute__((address_space(1))) void*)(aSrc + rowK16 + kt),
                                     (__attribute__((address_space(3))) void*)(aDst + 512), 16, 0, 0);
    __builtin_amdgcn_global_load_lds((const __attribute__((address_space(1))) void*)(bSrc + kt),
                                     (__attribute__((address_space(3))) void*)(bDst), 16, 0, 0);
    __builtin_amdgcn_global_load_lds((const __attribute__((address_space(1))) void*)(bSrc + rowK16 + kt),
                                     (__attribute__((address_space(3))) void*)(bDst + 512), 16, 0, 0);
    __syncthreads();  // compiler drains vmcnt before s_barrier -> LDS valid

    bf16x8 a[4], b[4];
#pragma unroll
    for (int mi = 0; mi < 4; ++mi)
      a[mi] = *(const bf16x8*)(As + (wr * 64 + mi * 16 + fr) * 32 + k8);
#pragma unroll
    for (int ni = 0; ni < 4; ++ni)
      b[ni] = *(const bf16x8*)(Bs + (wc * 64 + ni * 16 + fr) * 32 + k8);
#pragma unroll
    for (int mi = 0; mi < 4; ++mi)
#pragma unroll
      for (int ni = 0; ni < 4; ++ni)
        acc[mi][ni] = __builtin_amdgcn_mfma_f32_16x16x32_bf16(a[mi], b[ni], acc[mi][ni], 0, 0, 0);
  }
}

// ---------------------------------------------------------------------------
// Kernels
// ---------------------------------------------------------------------------

__global__ void convert_x_kernel(const float* __restrict__ x, u16* __restrict__ xb) {
  int i = blockIdx.x * 256 + threadIdx.x;       // 2,097,152 threads * 4 floats
  float4 f = ((const float4*)x)[i];
  u16x4 o = { f2bf(f.x), f2bf(f.y), f2bf(f.z), f2bf(f.w) };
  ((u16x4*)xb)[i] = o;
}

// W[m][d][e] f32 -> Wt[m][e][d] bf16 (LDS-tiled transpose)
__global__ void convw_kernel(const float* __restrict__ W, u16* __restrict__ wT) {
  __shared__ float tile[32][33];
  const int mtx = blockIdx.z;
  const int e0 = blockIdx.x * 32, d0 = blockIdx.y * 32;
  const int tx = threadIdx.x, ty = threadIdx.y;  // (32, 8)
  const float* Wm = W + (size_t)mtx * 262144;
#pragma unroll
  for (int i = 0; i < 32; i += 8)
    tile[ty + i][tx] = Wm[(size_t)(d0 + ty + i) * 512 + e0 + tx];
  __syncthreads();
  u16* T = wT + (size_t)mtx * 262144;
#pragma unroll
  for (int i = 0; i < 32; i += 8)
    T[(size_t)(e0 + ty + i) * 512 + d0 + tx] = f2bf(tile[tx][ty + i]);
}

// QKV: xb[16384,512] . Wt[1536,512]^T ; q,k stored [16384,512], v stored
// transposed per batch vt[b][512][2048].
__global__ __launch_bounds__(256) void gemm_qkv_kernel(
    const u16* __restrict__ xb, const u16* __restrict__ wT,
    u16* __restrict__ qb, u16* __restrict__ kb, u16* __restrict__ vt)
{
  __shared__ __align__(16) u16 As[4096], Bs[4096];
  const int n0 = blockIdx.x * 128, m0 = blockIdx.y * 128;
  f32x4 acc[4][4] = {};
  gemm_bt_mainloop(xb + (size_t)m0 * 512, wT + (size_t)n0 * 512, 512, As, Bs, acc);

  const int tid = threadIdx.x, w = tid >> 6, l = tid & 63;
  const int wr = w >> 1, wc = w & 1;
  const int which = n0 >> 9;                 // 0=q 1=k 2=v
  const int e0 = (n0 & 511) + wc * 64;
  const int r0 = m0 + wr * 64;
  if (which < 2) {
    u16* dst = which ? kb : qb;
#pragma unroll
    for (int mi = 0; mi < 4; ++mi)
#pragma unroll
      for (int ni = 0; ni < 4; ++ni) {
        const int rowb = r0 + mi * 16 + (l >> 4) * 4;
        const int col = e0 + ni * 16 + (l & 15);
#pragma unroll
        for (int r = 0; r < 4; ++r)
          dst[(size_t)(rowb + r) * 512 + col] = f2bf(acc[mi][ni][r]);
      }
  } else {
#pragma unroll
    for (int mi = 0; mi < 4; ++mi)
#pragma unroll
      for (int ni = 0; ni < 4; ++ni) {
        const int s = r0 + mi * 16 + (l >> 4) * 4;   // global row (b*2048+s)
        const int b = s >> 11, sl = s & 2047;
        const int e = e0 + ni * 16 + (l & 15);
        u16x4 pk;
#pragma unroll
        for (int r = 0; r < 4; ++r) pk[r] = f2bf(acc[mi][ni][r]);
        *(u16x4*)(vt + (size_t)b * 1048576 + (size_t)e * 2048 + sl) = pk;
      }
  }
}

// scores[z] = Q[z] . K[z]^T * 0.125 -> bf16
__global__ __launch_bounds__(256) void gemm_scores_kernel(
    const u16* __restrict__ qb, const u16* __restrict__ kb, u16* __restrict__ attn)
{
  __shared__ __align__(16) u16 As[4096], Bs[4096];
  const int z = blockIdx.z;
  const int n0 = blockIdx.x * 128, m0 = blockIdx.y * 128;
  f32x4 acc[4][4] = {};
  gemm_bt_mainloop(qb + (size_t)z * 1048576 + (size_t)m0 * 512,
                   kb + (size_t)z * 1048576 + (size_t)n0 * 512, 512, As, Bs, acc);
  const int tid = threadIdx.x, w = tid >> 6, l = tid & 63;
  const int wr = w >> 1, wc = w & 1;
  u16* C = attn + (size_t)z * 4194304;
#pragma unroll
  for (int mi = 0; mi < 4; ++mi)
#pragma unroll
    for (int ni = 0; ni < 4; ++ni) {
      const int rowb = m0 + wr * 64 + mi * 16 + (l >> 4) * 4;
      const int col = n0 + wc * 64 + ni * 16 + (l & 15);
#pragma unroll
      for (int r = 0; r < 4; ++r)
        C[(size_t)(rowb + r) * 2048 + col] = f2bf(acc[mi][ni][r] * 0.125f);
    }
}

// row softmax in place, bf16 storage, fp32 math. one block per row of 2048.
__global__ __launch_bounds__(256) void softmax_kernel(u16* __restrict__ attn) {
  __shared__ float redm[4], reds[4];
  const size_t row = blockIdx.x;
  u16* p = attn + row * 2048;
  const int t = threadIdx.x, w = t >> 6, l = t & 63;

  uint4 u = ((const uint4*)p)[t];
  u16* us = (u16*)&u;
  float v[8];
#pragma unroll
  for (int i = 0; i < 8; ++i) v[i] = bf2f(us[i]);

  float m = v[0];
#pragma unroll
  for (int i = 1; i < 8; ++i) m = fmaxf(m, v[i]);
  for (int off = 32; off >= 1; off >>= 1) m = fmaxf(m, __shfl_xor(m, off));
  if (l == 0) redm[w] = m;
  __syncthreads();
  m = fmaxf(fmaxf(redm[0], redm[1]), fmaxf(redm[2], redm[3]));

  float e[8], s = 0.f;
#pragma unroll
  for (int i = 0; i < 8; ++i) { e[i] = __expf(v[i] - m); s += e[i]; }
  for (int off = 32; off >= 1; off >>= 1) s += __shfl_xor(s, off);
  if (l == 0) reds[w] = s;
  __syncthreads();
  s = reds[0] + reds[1] + reds[2] + reds[3];
  const float inv = 1.f / s;

#pragma unroll
  for (int i = 0; i < 8; ++i) us[i] = f2bf(e[i] * inv);
  ((uint4*)p)[t] = u;
}

// out[z] = P[z][2048,2048] . V[z]  (V held transposed: vt[z][512][2048]) -> f32
__global__ __launch_bounds__(256) void gemm_pv_kernel(
    const u16* __restrict__ attn, const u16* __restrict__ vt, float* __restrict__ out)
{
  __shared__ __align__(16) u16 As[4096], Bs[4096];
  const int z = blockIdx.z;
  const int n0 = blockIdx.x * 128, m0 = blockIdx.y * 128;
  f32x4 acc[4][4] = {};
  gemm_bt_mainloop(attn + (size_t)z * 4194304 + (size_t)m0 * 2048,
                   vt + (size_t)z * 1048576 + (size_t)n0 * 2048, 2048, As, Bs, acc);
  const int tid = threadIdx.x, w = tid >> 6, l = tid & 63;
  const int wr = w >> 1, wc = w & 1;
  float* C = out + (size_t)z * 1048576;
#pragma unroll
  for (int mi = 0; mi < 4; ++mi)
#pragma unroll
    for (int ni = 0; ni < 4; ++ni) {
      const int rowb = m0 + wr * 64 + mi * 16 + (l >> 4) * 4;
      const int col = n0 + wc * 64 + ni * 16 + (l & 15);
#pragma unroll
      for (int r = 0; r < 4; ++r)
        C[(size_t)(rowb + r) * 512 + col] = acc[mi][ni][r];
    }
}

// ---------------------------------------------------------------------------
extern "C" void kernel_launch(void* const* d_in, const int* in_sizes, int n_in,
                              void* d_out, int out_size, void* d_ws, size_t ws_size,
                              hipStream_t stream) {
  const float* x = (const float*)d_in[0];   // [8,2048,512]
  const float* W = (const float*)d_in[1];   // [3,512,512]
  float* out = (float*)d_out;               // [8,2048,512]

  // workspace layout (u16 elems): qb | kb | vt | attn(67MB; xb+wT aliased in)
  if (ws_size < 117440512) return;          // 112 MiB needed
  u16* wsu  = (u16*)d_ws;
  u16* qb   = wsu;
  u16* kb   = qb + 8388608;
  u16* vt   = kb + 8388608;
  u16* attn = vt + 8388608;                 // 33,554,432 elems
  u16* xb   = attn;                         // alias: dead before scores written
  u16* wT   = attn + 8388608;               // alias: dead before scores written

  convert_x_kernel<<<8192, 256, 0, stream>>>(x, xb);
  convw_kernel<<<dim3(16, 16, 3), dim3(32, 8), 0, stream>>>(W, wT);
  gemm_qkv_kernel<<<dim3(12, 128), 256, 0, stream>>>(xb, wT, qb, kb, vt);
  gemm_scores_kernel<<<dim3(16, 16, 8), 256, 0, stream>>>(qb, kb, attn);
  softmax_kernel<<<16384, 256, 0, stream>>>(attn);
  gemm_pv_kernel<<<dim3(4, 16, 8), 256, 0, stream>>>(attn, vt, out);
}